// Round 9
// baseline (1468.886 us; speedup 1.0000x reference)
//
#include <hip/hip_runtime.h>
#include <math.h>

// ---------------- problem constants ----------------
#define BB 4
#define NN 20000
#define CC 256
#define VV 300
#define SS 1024
#define CPKS 20480   // cpk per-batch stride (ceil(20000/512)*512)
#define W1MAX 3072   // max M handled by the 8-wave FPS (6 chunks * 512 threads)

// output float offsets (concatenated flat, all read back as float32)
#define O_GRASP   0          // (4,20000)
#define O_OBJ     80000      // (4,20000)
#define O_GXYZ    160000     // (4,1024,3)
#define O_INDS    172288     // (4,1024)
#define O_GFEAT   176384     // (4,256,1024)
#define O_FPG     1224960    // (4,1024)
#define O_VIEW    1229056    // (4,1024,300)
#define O_TVI     2457856    // (4,1024)
#define O_TVS     2461952    // (4,1024)
#define O_VPX     2466048    // (4,1024,3)
#define O_VPR     2478336    // (4,1024,3,3)

// ws float offsets
#define W_GH1T    0          // [256 c][256 o]
#define W_W1T     65536      // [256 c][256 o]
#define W_W2T     131072     // [256 c][320 o-pad] (O=300)
#define W_W3T     212992     // [300 c][320 o-pad] (O=300)
#define W_TMPL    308992     // 300*3
#define W_SGH     309892     // 256
#define W_SC1     310148     // 256
#define W_SC2     310404     // 300
#define W_CNT     310704     // 4 ints (pad to 310720)
#define W_CPK     310720     // 4*20480 float4 (x,y,z,~idx-bits)
#define W_INDS    638400     // 4*1024 int
#define W_MASK    642496     // 4*20000 int
#define W_F1      722496     // 4*256*1024
#define W_F2      1771072    // 4*300*1024  (end 2999872 floats = 12 MB)

// FMA a 4-vector accumulator: A += W * X (componentwise), exact fmaf per element.
#define FMA4(A, W, X) do { \
    A.x = fmaf((W), (X).x, A.x); \
    A.y = fmaf((W), (X).y, A.y); \
    A.z = fmaf((W), (X).z, A.z); \
    A.w = fmaf((W), (X).w, A.w); } while (0)

__device__ __forceinline__ float4 bnrelu4(float4 a, float bb, float mm, float ssv, float ee) {
    float4 r;
    r.x = fmaxf(__fadd_rn(__fmul_rn(__fsub_rn(__fadd_rn(a.x, bb), mm), ssv), ee), 0.0f);
    r.y = fmaxf(__fadd_rn(__fmul_rn(__fsub_rn(__fadd_rn(a.y, bb), mm), ssv), ee), 0.0f);
    r.z = fmaxf(__fadd_rn(__fmul_rn(__fsub_rn(__fadd_rn(a.z, bb), mm), ssv), ee), 0.0f);
    r.w = fmaxf(__fadd_rn(__fmul_rn(__fsub_rn(__fadd_rn(a.w, bb), mm), ssv), ee), 0.0f);
    return r;
}

// ---- DPP-based wave64 max reduction on u64 keys (result broadcast to all lanes) ----
template <int CTRL>
__device__ __forceinline__ unsigned long long wmax_step(unsigned long long k) {
    int lo = (int)(unsigned int)k;
    int hi = (int)(unsigned int)(k >> 32);
    int plo = __builtin_amdgcn_update_dpp(lo, lo, CTRL, 0xf, 0xf, false);
    int phi = __builtin_amdgcn_update_dpp(hi, hi, CTRL, 0xf, 0xf, false);
    unsigned long long p = ((unsigned long long)(unsigned int)phi << 32) | (unsigned int)plo;
    return (p > k) ? p : k;
}
__device__ __forceinline__ unsigned long long wave_max_u64(unsigned long long k) {
    k = wmax_step<0x111>(k);   // row_shr:1
    k = wmax_step<0x112>(k);   // row_shr:2
    k = wmax_step<0x114>(k);   // row_shr:4
    k = wmax_step<0x118>(k);   // row_shr:8  -> lane15 of each row has row max
    k = wmax_step<0x142>(k);   // row_bcast15
    k = wmax_step<0x143>(k);   // row_bcast31 -> lane63 has wave max
    unsigned int lo = (unsigned int)__builtin_amdgcn_readlane((int)(unsigned int)k, 63);
    unsigned int hi = (unsigned int)__builtin_amdgcn_readlane((int)(unsigned int)(k >> 32), 63);
    return ((unsigned long long)hi << 32) | lo;
}

// ---- legacy register-resident storage (used by the >3072 fallback only) ----
// cpk.w stores ~n bits directly (sentinel stores 0).
template <int N> struct Pts {
    Pts<N - 1> rest;
    float px, py, pz, dist;
    unsigned int klo;
};
template <> struct Pts<0> {};

template <int N, int SH, int J0>
__device__ __forceinline__ void pts_load(Pts<N>& P, const float4* __restrict__ base,
                                         int t, int M,
                                         unsigned long long& bkey, float& bx, float& by, float& bz) {
    if constexpr (N > 0) {
        pts_load<N - 1, SH, J0>(P.rest, base, t, M, bkey, bx, by, bz);
        constexpr int J = J0 + N - 1;
        if ((J << SH) < M) {
            float4 v = base[t + (J << SH)];
            P.px = v.x; P.py = v.y; P.pz = v.z;
            P.klo = __float_as_uint(v.w);        // already ~n (pad -> 0)
            P.dist = (P.klo != 0u) ? 1e10f : 0.0f;
            unsigned long long k = ((unsigned long long)__float_as_uint(P.dist) << 32) | P.klo;
            if (k > bkey) { bkey = k; bx = v.x; by = v.y; bz = v.z; }
        } else {
            P.px = P.py = P.pz = 0.0f; P.dist = 0.0f; P.klo = 0u;
        }
    }
}

template <int N, int SH, int J0>
__device__ __forceinline__ void pts_upd(Pts<N>& P, int t, int M,
                                        float cx, float cy, float cz,
                                        unsigned long long& bkey, float& bx, float& by, float& bz) {
    if constexpr (N > 0) {
        pts_upd<N - 1, SH, J0>(P.rest, t, M, cx, cy, cz, bkey, bx, by, bz);
        constexpr int J = J0 + N - 1;
        if ((J << SH) < M) {
            float dx = __fsub_rn(P.px, cx);
            float dy = __fsub_rn(P.py, cy);
            float dz = __fsub_rn(P.pz, cz);
            float d = __fadd_rn(__fadd_rn(__fmul_rn(dx, dx), __fmul_rn(dy, dy)), __fmul_rn(dz, dz));
            float nd = fminf(P.dist, d);
            P.dist = nd;
            unsigned long long k = ((unsigned long long)__float_as_uint(nd) << 32) | P.klo;
            if (k > bkey) { bkey = k; bx = P.px; by = P.py; bz = P.pz; }
        }
    }
}

// ---------------- K0: prep (transposes, bn scales, templates, cnt=0) ----------------
__global__ void k0_prep(const float* __restrict__ w_gh1, const float* __restrict__ w1,
                        const float* __restrict__ w2, const float* __restrict__ w3,
                        const float* __restrict__ gh_g, const float* __restrict__ gh_v,
                        const float* __restrict__ g1, const float* __restrict__ v1,
                        const float* __restrict__ g2, const float* __restrict__ v2,
                        float* __restrict__ ws) {
    int id = blockIdx.x * 256 + threadIdx.x;
    if (id < 65536) {
        int k = id & 255, o = id >> 8;
        ws[W_GH1T + k * 256 + o] = w_gh1[id];
    } else if (id < 131072) {
        int l = id - 65536; int k = l & 255, o = l >> 8;
        ws[W_W1T + k * 256 + o] = w1[l];
    } else if (id < 207872) {
        int l = id - 131072; int k = l & 255, o = l >> 8;
        ws[W_W2T + k * 320 + o] = w2[l];
    } else if (id < 297872) {
        int l = id - 207872; int k = l % 300, o = l / 300;
        ws[W_W3T + k * 320 + o] = w3[l];
    } else if (id < 298172) {
        int i = id - 297872;
        double phi = (sqrt(5.0) - 1.0) / 2.0;
        double zi = (2.0 * (double)i + 1.0) / 300.0 - 1.0;
        double r2 = 1.0 - zi * zi; if (r2 < 0.0) r2 = 0.0;
        double ri = sqrt(r2);
        double th = (6.283185307179586 * (double)i) * phi;
        ws[W_TMPL + i * 3 + 0] = (float)(ri * cos(th));
        ws[W_TMPL + i * 3 + 1] = (float)(ri * sin(th));
        ws[W_TMPL + i * 3 + 2] = (float)zi;
    } else if (id < 298428) {
        int i = id - 298172; ws[W_SGH + i] = gh_g[i] / sqrtf(gh_v[i] + 1e-5f);
    } else if (id < 298684) {
        int i = id - 298428; ws[W_SC1 + i] = g1[i] / sqrtf(v1[i] + 1e-5f);
    } else if (id < 298984) {
        int i = id - 298684; ws[W_SC2 + i] = g2[i] / sqrtf(v2[i] + 1e-5f);
    } else if (id < 298988) {
        ((int*)(ws + W_CNT))[id - 298984] = 0;
    }
}

// ---------------- K1: fused stage A (64-wide n-tile, named float4 accumulators) ----------------
__global__ __launch_bounds__(256)
__attribute__((amdgpu_waves_per_eu(2, 2)))
void k1_stageA(
    const float* __restrict__ x,       // seed_features (B,256,20000)
    const float* __restrict__ wt,      // gh_w1^T [c][256]
    const float* __restrict__ b1g, const float* __restrict__ scg,
    const float* __restrict__ m1g, const float* __restrict__ be1g,
    const float* __restrict__ w2g, const float* __restrict__ b2g,   // (3,256),(3)
    float* __restrict__ out_grasp, float* __restrict__ out_obj, int* __restrict__ maskw) {
    __shared__ __align__(16) float Xs[256 * 64];   // 64 KB
    int b = blockIdx.y;
    int n0 = blockIdx.x * 64;
    int t = threadIdx.x;
    const float* xb = x + (size_t)b * CC * NN;
    #pragma unroll
    for (int k = 0; k < 16; k++) {
        int id = t + k * 256; int c = id >> 4; int u = id & 15;
        int n = n0 + u * 4;
        float4 v = make_float4(0.f, 0.f, 0.f, 0.f);
        if (n < NN) v = *(const float4*)(xb + (size_t)c * NN + n);
        *(float4*)(Xs + c * 64 + u * 4) = v;
    }
    __syncthreads();
    int og = (t >> 3) * 8;
    int n8 = (t & 7) * 8;
    float4 a0l = {0,0,0,0}, a0h = {0,0,0,0}, a1l = {0,0,0,0}, a1h = {0,0,0,0};
    float4 a2l = {0,0,0,0}, a2h = {0,0,0,0}, a3l = {0,0,0,0}, a3h = {0,0,0,0};
    float4 a4l = {0,0,0,0}, a4h = {0,0,0,0}, a5l = {0,0,0,0}, a5h = {0,0,0,0};
    float4 a6l = {0,0,0,0}, a6h = {0,0,0,0}, a7l = {0,0,0,0}, a7h = {0,0,0,0};
    #pragma unroll 2
    for (int c = 0; c < 256; c++) {
        float4 wva = *(const float4*)(wt + c * 256 + og);
        float4 wvb = *(const float4*)(wt + c * 256 + og + 4);
        float4 xva = *(const float4*)(Xs + c * 64 + n8);
        float4 xvb = *(const float4*)(Xs + c * 64 + n8 + 4);
        FMA4(a0l, wva.x, xva); FMA4(a0h, wva.x, xvb);
        FMA4(a1l, wva.y, xva); FMA4(a1h, wva.y, xvb);
        FMA4(a2l, wva.z, xva); FMA4(a2h, wva.z, xvb);
        FMA4(a3l, wva.w, xva); FMA4(a3h, wva.w, xvb);
        FMA4(a4l, wvb.x, xva); FMA4(a4h, wvb.x, xvb);
        FMA4(a5l, wvb.y, xva); FMA4(a5h, wvb.y, xvb);
        FMA4(a6l, wvb.z, xva); FMA4(a6h, wvb.z, xvb);
        FMA4(a7l, wvb.w, xva); FMA4(a7h, wvb.w, xvb);
    }
    __syncthreads();   // all reads of Xs done; reuse as h-tile
#define K1_EPI(I) { int o = og + I; \
    float bb = b1g[o], mm = m1g[o], ssv = scg[o], ee = be1g[o]; \
    *(float4*)(Xs + o * 64 + n8)     = bnrelu4(a##I##l, bb, mm, ssv, ee); \
    *(float4*)(Xs + o * 64 + n8 + 4) = bnrelu4(a##I##h, bb, mm, ssv, ee); }
    K1_EPI(0) K1_EPI(1) K1_EPI(2) K1_EPI(3)
    K1_EPI(4) K1_EPI(5) K1_EPI(6) K1_EPI(7)
#undef K1_EPI
    __syncthreads();
    if (t < 64) {
        float s0a = 0.0f, s1a = 0.0f, s2a = 0.0f;
        for (int c = 0; c < 256; c++) {
            float xv = Xs[c * 64 + t];
            s0a = fmaf(xv, w2g[c], s0a);
            s1a = fmaf(xv, w2g[256 + c], s1a);
            s2a = fmaf(xv, w2g[512 + c], s2a);
        }
        int n = n0 + t;
        if (n < NN) {
            float s0 = __fadd_rn(s0a, b2g[0]);
            float s1 = __fadd_rn(s1a, b2g[1]);
            float s2 = __fadd_rn(s2a, b2g[2]);
            bool obj = s1 > s0;
            bool gr = obj && (s2 > 0.1f);
            int gn = b * NN + n;
            out_grasp[gn] = s2;
            out_obj[gn] = obj ? 1.0f : 0.0f;
            maskw[gn] = gr ? 1 : 0;
        }
    }
}

// ---------------- K2: compact masked points (wave-aggregated atomics) ----------------
// w stores ~n bits (klo) directly.
__global__ void k2_compact(const float* __restrict__ sx, const int* __restrict__ maskr,
                           int* __restrict__ cnt, float4* __restrict__ cpk) {
    int n = blockIdx.x * 256 + threadIdx.x;
    int b = blockIdx.y;
    bool take = (n < NN) && (maskr[b * NN + n] != 0);
    unsigned long long m = __ballot(take);
    if (take) {
        int lane = threadIdx.x & 63;
        int lead = __ffsll((long long)m) - 1;
        int base = 0;
        if (lane == lead) base = atomicAdd(cnt + b, __popcll(m));
        base = __shfl(base, lead);
        int pos = base + __popcll(m & ((1ull << lane) - 1ull));
        const float* p = sx + ((size_t)b * NN + n) * 3;
        cpk[b * CPKS + pos] = make_float4(p[0], p[1], p[2], __uint_as_float(~(unsigned int)n));
    }
}

// ---------------- K2b: pad cpk to a 512-multiple with sentinel points ----------------
__global__ void k2_pad(const int* __restrict__ cnt, float4* __restrict__ cpk) {
    int b = blockIdx.x;
    int M = cnt[b];
    int Mpad = (M + 511) & ~511;
    for (int i = M + threadIdx.x; i < Mpad; i += 512)
        cpk[b * CPKS + i] = make_float4(0.f, 0.f, 0.f, __uint_as_float(0u));
}

// ---------------- K3w8: FPS — 8 waves (2/SIMD), register-resident, slim exchange ----------------
// r8 post-mortem: w4 = 1640 cyc/step at 52% active-SIMD issue -> ~790 cyc of
// un-hidden latency (combine ds_reads, DPP chain, publish->barrier->read) with
// 1 wave/SIMD. 2 waves/SIMD keeps per-SIMD issue work identical (2 x half the
// points) but interleaves the latency-heavy exchange sections. R1's 8-wave
// failure was the in-loop global-store vmcnt drain — now removed.
// Publish: winner lane is unique (bkey==wkey); all-sentinel-wave ties write
// identical data (benign).
template <int NCH>
__global__ __launch_bounds__(512)
__attribute__((amdgpu_waves_per_eu(2, 2)))
void k3_fps_w8(const float4* __restrict__ cpk,
               const int* __restrict__ cnt,
               float* __restrict__ out_inds,
               int* __restrict__ inds_i) {
    __shared__ unsigned long long skey[2][8];
    __shared__ __align__(16) float4 scd[2][8];
    __shared__ unsigned int res[SS];
    int b = blockIdx.x;
    int t = threadIdx.x;
    int wid = t >> 6;
    int M = __builtin_amdgcn_readfirstlane(cnt[b]);
    if constexpr (NCH == 1) {
        if (M == 0) {
            for (int s = t; s < SS; s += 512) { out_inds[b * SS + s] = 0.0f; inds_i[b * SS + s] = 0; }
            return;
        }
    }
    if (((M + 511) >> 9) != NCH) return;   // exactly one variant proceeds

    float px[NCH], py[NCH], pz[NCH], dist[NCH];
    unsigned int klo[NCH];
    unsigned long long bkey = 0ull;
    float bx = 0.0f, by = 0.0f, bz = 0.0f;
    const float4* gsrc = cpk + b * CPKS;
    // branch-free init: [0, NCH*512) is real data or sentinels (NCH*512 == Mpad512)
    #pragma unroll
    for (int j = 0; j < NCH; j++) {
        float4 v = gsrc[t + (j << 9)];
        px[j] = v.x; py[j] = v.y; pz[j] = v.z;
        klo[j] = __float_as_uint(v.w);            // ~n; pad -> 0
        dist[j] = (klo[j] != 0u) ? 1e10f : 0.0f;  // sentinel -> key 0 forever
        unsigned long long k = ((unsigned long long)__float_as_uint(dist[j]) << 32) | klo[j];
        bool g = k > bkey;
        bkey = g ? k : bkey;
        bx = g ? v.x : bx; by = g ? v.y : by; bz = g ? v.z : bz;
    }
    // publish initial per-wave winner (winner lane unique; sentinel ties identical)
    {
        unsigned long long wkey = wave_max_u64(bkey);
        if (bkey == wkey) {
            skey[0][wid] = wkey;
            scd[0][wid] = make_float4(bx, by, bz, 0.0f);
        }
    }
    __syncthreads();
    int buf = 0;
    for (int step = 0; step < SS; step++) {
        // slim 8-slot combine (broadcast LDS reads, all threads)
        unsigned long long wk = skey[buf][0];
        float4 c = scd[buf][0];
        #pragma unroll
        for (int i = 1; i < 8; i++) {
            unsigned long long k2 = skey[buf][i];
            float4 c2 = scd[buf][i];
            if (k2 > wk) { wk = k2; c = c2; }
        }
        if (t == 0) res[step] = (unsigned int)(wk & 0xFFFFFFFFull);   // klo; ~ at writeback
        if (step == SS - 1) break;   // last selection needs no update
        float cx = c.x, cy = c.y, cz = c.z;
        bkey = 0ull; bx = by = bz = 0.0f;
        #pragma unroll
        for (int j = 0; j < NCH; j++) {
            float dx = __fsub_rn(px[j], cx);
            float dy = __fsub_rn(py[j], cy);
            float dz = __fsub_rn(pz[j], cz);
            float d = __fadd_rn(__fadd_rn(__fmul_rn(dx, dx), __fmul_rn(dy, dy)), __fmul_rn(dz, dz));
            float nd = fminf(dist[j], d);
            dist[j] = nd;
            unsigned long long k = ((unsigned long long)__float_as_uint(nd) << 32) | klo[j];
            bool g = k > bkey;
            bkey = g ? k : bkey;
            bx = g ? px[j] : bx; by = g ? py[j] : by; bz = g ? pz[j] : bz;
        }
        unsigned long long wkey = wave_max_u64(bkey);
        if (bkey == wkey) {
            skey[buf ^ 1][wid] = wkey;
            scd[buf ^ 1][wid] = make_float4(bx, by, bz, 0.0f);
        }
        __syncthreads();   // no outstanding global ops in-loop -> cheap drain
        buf ^= 1;
    }
    __syncthreads();
    for (int s = t; s < SS; s += 512) {
        unsigned int cid = ~res[s];
        out_inds[b * SS + s] = (float)cid;
        inds_i[b * SS + s] = (int)cid;
    }
}

// ---------------- K3: FPS fallback — 512 thr / 8 waves (only if M > W1MAX) ----------------
template <int G>
__global__ __launch_bounds__(512)
__attribute__((amdgpu_waves_per_eu(2, 2)))
void k3_fps(const float4* __restrict__ cpk,
            const int* __restrict__ cnt,
            float* __restrict__ out_inds,
            int* __restrict__ inds_i, int minM) {
    int b = blockIdx.x;
    int t = threadIdx.x;
    int M = __builtin_amdgcn_readfirstlane(cnt[b]);
    if (M <= minM) return;   // 8-wave kernel already handled this batch
    __shared__ unsigned long long skey[2][8];
    __shared__ __align__(16) float4 scd[2][8];
    Pts<G> Pa, Pb;
    int wid = t >> 6, lane = t & 63;
    unsigned long long bkey = 0ull;
    float bx = 0, by = 0, bz = 0;
    const float4* base = cpk + b * CPKS;
    pts_load<G, 9, 0>(Pa, base, t, M, bkey, bx, by, bz);
    pts_load<G, 9, G>(Pb, base, t, M, bkey, bx, by, bz);
    {
        unsigned long long wkey = wave_max_u64(bkey);
        unsigned long long mb = __ballot(bkey == wkey);
        if (lane == __ffsll((long long)mb) - 1) {
            skey[0][wid] = wkey;
            scd[0][wid] = make_float4(bx, by, bz, 0.0f);
        }
    }
    __syncthreads();
    int buf = 0;
    for (int step = 0; step < SS; step++) {
        unsigned long long wk = skey[buf][0];
        float4 c = scd[buf][0];
        #pragma unroll
        for (int i = 1; i < 8; i++) {
            unsigned long long k2 = skey[buf][i];
            float4 c2 = scd[buf][i];
            if (k2 > wk) { wk = k2; c = c2; }
        }
        unsigned int cid = ~(unsigned int)(wk & 0xFFFFFFFFull);
        if (t == 0) { out_inds[b * SS + step] = (float)cid; inds_i[b * SS + step] = (int)cid; }
        bkey = 0ull; bx = by = bz = 0.0f;
        pts_upd<G, 9, 0>(Pa, t, M, c.x, c.y, c.z, bkey, bx, by, bz);
        pts_upd<G, 9, G>(Pb, t, M, c.x, c.y, c.z, bkey, bx, by, bz);
        unsigned long long wkey = wave_max_u64(bkey);
        unsigned long long mb = __ballot(bkey == wkey);
        if (lane == __ffsll((long long)mb) - 1) {
            skey[buf ^ 1][wid] = wkey;
            scd[buf ^ 1][wid] = make_float4(bx, by, bz, 0.0f);
        }
        __syncthreads();
        buf ^= 1;
    }
}

// ---------------- K4a: feature gather (one thread per output element) ----------------
__global__ void k4_gatherF(const float* __restrict__ sf, const int* __restrict__ inds,
                           float* __restrict__ o_feat) {
    int id = blockIdx.x * 256 + threadIdx.x;   // B*C*S = 1,048,576
    int s = id & (SS - 1);
    int bc = id >> 10;                          // b*C + c
    int b = bc >> 8;
    int idx = inds[(b << 10) | s];
    o_feat[id] = sf[(size_t)bc * NN + idx];
}

// ---------------- K4b: xyz + graspness gather ----------------
__global__ void k4_gatherX(const float* __restrict__ sx, const int* __restrict__ inds,
                           const float* __restrict__ grasp_all,
                           float* __restrict__ o_xyz, float* __restrict__ o_fg) {
    int id = blockIdx.x * 256 + threadIdx.x;   // 4096
    int b = id >> 10;
    int idx = inds[id];
    const float* p = sx + ((size_t)b * NN + idx) * 3;
    o_xyz[id * 3 + 0] = p[0];
    o_xyz[id * 3 + 1] = p[1];
    o_xyz[id * 3 + 2] = p[2];
    o_fg[id] = grasp_all[b * NN + idx];
}

// ---------------- K5: generic conv1x1 GEMM over 1024 pts (+optional bn+relu) ----------------
__global__ __launch_bounds__(256)
__attribute__((amdgpu_waves_per_eu(2, 2)))
void k5_gemm(const float* __restrict__ X, const float* __restrict__ WT,
             const float* __restrict__ bias, const float* __restrict__ scale,
             const float* __restrict__ mean, const float* __restrict__ beta,
             float* __restrict__ Y, int O, int Opad, int K, int relu_bn) {
    __shared__ __align__(16) float Xs[64 * 64];
    int b = blockIdx.z;
    int n0 = blockIdx.y * 64;
    int o0 = blockIdx.x * 64;
    int t = threadIdx.x;
    int o4 = o0 + (t & 15) * 4;
    int n4 = (t >> 4) * 4;
    float4 ac0 = {0,0,0,0}, ac1 = {0,0,0,0}, ac2 = {0,0,0,0}, ac3 = {0,0,0,0};
    const float* Xb = X + (size_t)b * K * SS;
    for (int c0 = 0; c0 < K; c0 += 64) {
        #pragma unroll
        for (int k = 0; k < 4; k++) {
            int id = t + k * 256; int cc = id >> 4; int nn4 = (id & 15) * 4;
            int c = c0 + cc;
            float4 v = make_float4(0.f, 0.f, 0.f, 0.f);
            if (c < K) v = *(const float4*)(Xb + (size_t)c * SS + n0 + nn4);
            *(float4*)(Xs + cc * 64 + nn4) = v;
        }
        __syncthreads();
        int kmax = (K - c0 < 64) ? (K - c0) : 64;
        for (int cc = 0; cc < kmax; cc++) {
            float4 wv = *(const float4*)(WT + (size_t)(c0 + cc) * Opad + o4);
            float4 xv = *(const float4*)(Xs + cc * 64 + n4);
            FMA4(ac0, wv.x, xv);
            FMA4(ac1, wv.y, xv);
            FMA4(ac2, wv.z, xv);
            FMA4(ac3, wv.w, xv);
        }
        __syncthreads();
    }
#define K5_EPI(I) { int o = o4 + I; if (o < O) { \
    float bb = bias[o]; float4 v; \
    if (relu_bn) { v = bnrelu4(ac##I, bb, mean[o], scale[o], beta[o]); } \
    else { v.x = __fadd_rn(ac##I.x, bb); v.y = __fadd_rn(ac##I.y, bb); \
           v.z = __fadd_rn(ac##I.z, bb); v.w = __fadd_rn(ac##I.w, bb); } \
    *(float4*)(Y + ((size_t)b * O + o) * SS + n0 + n4) = v; } }
    K5_EPI(0) K5_EPI(1) K5_EPI(2) K5_EPI(3)
#undef K5_EPI
}

// ---------------- K5t: layer-3 GEMM with TRANSPOSED epilogue (replaces K7) ----------------
// Writes Y[(b*SS + n)*VV + o] directly (s-major view_score). Same __fadd_rn
// arithmetic as k5_gemm's non-bn path; only the store layout differs.
__global__ __launch_bounds__(256)
__attribute__((amdgpu_waves_per_eu(2, 2)))
void k5_gemm_t(const float* __restrict__ X, const float* __restrict__ WT,
               const float* __restrict__ bias,
               float* __restrict__ Y, int Opad, int K) {
    __shared__ __align__(16) float Xs[64 * 64];
    int b = blockIdx.z;
    int n0 = blockIdx.y * 64;
    int o0 = blockIdx.x * 64;
    int t = threadIdx.x;
    int o4 = o0 + (t & 15) * 4;
    int n4 = (t >> 4) * 4;
    float4 ac0 = {0,0,0,0}, ac1 = {0,0,0,0}, ac2 = {0,0,0,0}, ac3 = {0,0,0,0};
    const float* Xb = X + (size_t)b * K * SS;
    for (int c0 = 0; c0 < K; c0 += 64) {
        #pragma unroll
        for (int k = 0; k < 4; k++) {
            int id = t + k * 256; int cc = id >> 4; int nn4 = (id & 15) * 4;
            int c = c0 + cc;
            float4 v = make_float4(0.f, 0.f, 0.f, 0.f);
            if (c < K) v = *(const float4*)(Xb + (size_t)c * SS + n0 + nn4);
            *(float4*)(Xs + cc * 64 + nn4) = v;
        }
        __syncthreads();
        int kmax = (K - c0 < 64) ? (K - c0) : 64;
        for (int cc = 0; cc < kmax; cc++) {
            float4 wv = *(const float4*)(WT + (size_t)(c0 + cc) * Opad + o4);
            float4 xv = *(const float4*)(Xs + cc * 64 + n4);
            FMA4(ac0, wv.x, xv);
            FMA4(ac1, wv.y, xv);
            FMA4(ac2, wv.z, xv);
            FMA4(ac3, wv.w, xv);
        }
        __syncthreads();
    }
    if (o4 + 3 < VV) {   // o4 multiple of 4; VV=300 -> o4 <= 296 fully in-bounds
        float4 bb4 = *(const float4*)(bias + o4);
#define K5T_ROW(J, CMP) { \
        float4 r; \
        r.x = __fadd_rn(ac0.CMP, bb4.x); \
        r.y = __fadd_rn(ac1.CMP, bb4.y); \
        r.z = __fadd_rn(ac2.CMP, bb4.z); \
        r.w = __fadd_rn(ac3.CMP, bb4.w); \
        *(float4*)(Y + ((size_t)b * SS + (n0 + n4 + J)) * VV + o4) = r; }
        K5T_ROW(0, x) K5T_ROW(1, y) K5T_ROW(2, z) K5T_ROW(3, w)
#undef K5T_ROW
    }
}

// ---------------- K6: view max/argmax + rotations (float4-vectorized scan) ----------------
__global__ void k6_view(const float* __restrict__ Vs,   // view_score (B,1024,300)
                        const float* __restrict__ tmpl,
                        float* __restrict__ o_ti, float* __restrict__ o_ts,
                        float* __restrict__ o_vx, float* __restrict__ o_vr) {
    int id = blockIdx.x * 256 + threadIdx.x;   // 4096
    // VV=300 divisible by 4 -> per-row byte offset divisible by 16: aligned float4
    const float4* f4 = (const float4*)(Vs + (size_t)id * VV);
    float best = -INFINITY;
    int bi = 0;
    #pragma unroll 5
    for (int g = 0; g < VV / 4; g++) {
        float4 x4 = f4[g];
        if (x4.x > best) { best = x4.x; bi = g * 4; }       // in-order strict > keeps
        if (x4.y > best) { best = x4.y; bi = g * 4 + 1; }   // first max (== reference)
        if (x4.z > best) { best = x4.z; bi = g * 4 + 2; }
        if (x4.w > best) { best = x4.w; bi = g * 4 + 3; }
    }
    o_ti[id] = (float)bi;
    o_ts[id] = best;
    float tx = tmpl[bi * 3 + 0], ty = tmpl[bi * 3 + 1], tz = tmpl[bi * 3 + 2];
    o_vx[id * 3 + 0] = tx; o_vx[id * 3 + 1] = ty; o_vx[id * 3 + 2] = tz;
    // towards = -vp_xyz
    float ax0 = -tx, ax1 = -ty, ax2 = -tz;
    float ay0 = ty, ay1 = -tx, ay2 = 0.0f;   // (-ax1, ax0, 0)
    float ny = sqrtf(__fadd_rn(__fadd_rn(__fmul_rn(ay0, ay0), __fmul_rn(ay1, ay1)), __fmul_rn(ay2, ay2)));
    if (ny == 0.0f) { ay0 = 0.0f; ay1 = 1.0f; ay2 = 0.0f; }
    float nx = sqrtf(__fadd_rn(__fadd_rn(__fmul_rn(ax0, ax0), __fmul_rn(ax1, ax1)), __fmul_rn(ax2, ax2)));
    ax0 = ax0 / nx; ax1 = ax1 / nx; ax2 = ax2 / nx;
    float ny2 = sqrtf(__fadd_rn(__fadd_rn(__fmul_rn(ay0, ay0), __fmul_rn(ay1, ay1)), __fmul_rn(ay2, ay2)));
    ay0 = ay0 / ny2; ay1 = ay1 / ny2; ay2 = ay2 / ny2;
    float az0 = __fsub_rn(__fmul_rn(ax1, ay2), __fmul_rn(ax2, ay1));
    float az1 = __fsub_rn(__fmul_rn(ax2, ay0), __fmul_rn(ax0, ay2));
    float az2 = __fsub_rn(__fmul_rn(ax0, ay1), __fmul_rn(ax1, ay0));
    float* R = o_vr + (size_t)id * 9;   // columns = (ax, ay, az)
    R[0] = ax0; R[1] = ay0; R[2] = az0;
    R[3] = ax1; R[4] = ay1; R[5] = az1;
    R[6] = ax2; R[7] = ay2; R[8] = az2;
}

extern "C" void kernel_launch(void* const* d_in, const int* in_sizes, int n_in,
                              void* d_out, int out_size, void* d_ws, size_t ws_size,
                              hipStream_t stream) {
    const float* seed_xyz  = (const float*)d_in[0];
    const float* seed_feat = (const float*)d_in[1];
    const float* gh_w1 = (const float*)d_in[2];
    const float* gh_b1 = (const float*)d_in[3];
    const float* gh_g1 = (const float*)d_in[4];
    const float* gh_be1 = (const float*)d_in[5];
    const float* gh_m1 = (const float*)d_in[6];
    const float* gh_v1 = (const float*)d_in[7];
    const float* gh_w2 = (const float*)d_in[8];
    const float* gh_b2 = (const float*)d_in[9];
    const float* w1 = (const float*)d_in[10];
    const float* b1 = (const float*)d_in[11];
    const float* g1 = (const float*)d_in[12];
    const float* be1 = (const float*)d_in[13];
    const float* m1 = (const float*)d_in[14];
    const float* v1 = (const float*)d_in[15];
    const float* w2 = (const float*)d_in[16];
    const float* b2 = (const float*)d_in[17];
    const float* g2 = (const float*)d_in[18];
    const float* be2 = (const float*)d_in[19];
    const float* m2 = (const float*)d_in[20];
    const float* v2 = (const float*)d_in[21];
    const float* w3 = (const float*)d_in[22];
    const float* b3 = (const float*)d_in[23];

    float* out = (float*)d_out;
    float* ws = (float*)d_ws;
    int* cnt = (int*)(ws + W_CNT);
    float4* cpk = (float4*)(ws + W_CPK);
    int* inds_i = (int*)(ws + W_INDS);
    int* maskw = (int*)(ws + W_MASK);

    // K0: prep
    k0_prep<<<dim3((298988 + 255) / 256), dim3(256), 0, stream>>>(
        gh_w1, w1, w2, w3, gh_g1, gh_v1, g1, v1, g2, v2, ws);

    // K1: fused stage A (64-wide tiles)
    k1_stageA<<<dim3((NN + 63) / 64, BB), dim3(256), 0, stream>>>(
        seed_feat, ws + W_GH1T, gh_b1, ws + W_SGH, gh_m1, gh_be1, gh_w2, gh_b2,
        out + O_GRASP, out + O_OBJ, maskw);

    // K2: compaction (wave-aggregated atomics) + sentinel padding to 512-multiple
    k2_compact<<<dim3((NN + 255) / 256, BB), dim3(256), 0, stream>>>(seed_xyz, maskw, cnt, cpk);
    k2_pad<<<dim3(BB), dim3(512), 0, stream>>>(cnt, cpk);

    // K3: FPS — 8-wave register-resident variants (NCH = ceil(M/512), M <= 3072)
    k3_fps_w8<1><<<dim3(BB), dim3(512), 0, stream>>>(cpk, cnt, out + O_INDS, inds_i);
    k3_fps_w8<2><<<dim3(BB), dim3(512), 0, stream>>>(cpk, cnt, out + O_INDS, inds_i);
    k3_fps_w8<3><<<dim3(BB), dim3(512), 0, stream>>>(cpk, cnt, out + O_INDS, inds_i);
    k3_fps_w8<4><<<dim3(BB), dim3(512), 0, stream>>>(cpk, cnt, out + O_INDS, inds_i);
    k3_fps_w8<5><<<dim3(BB), dim3(512), 0, stream>>>(cpk, cnt, out + O_INDS, inds_i);
    k3_fps_w8<6><<<dim3(BB), dim3(512), 0, stream>>>(cpk, cnt, out + O_INDS, inds_i);
    // fallback for M > 3072 (8 waves, register-resident)
    k3_fps<20><<<dim3(BB), dim3(512), 0, stream>>>(cpk, cnt, out + O_INDS, inds_i, W1MAX);

    // K4: gathers
    k4_gatherF<<<dim3(BB * CC * SS / 256), dim3(256), 0, stream>>>(seed_feat, inds_i, out + O_GFEAT);
    k4_gatherX<<<dim3(BB * SS / 256), dim3(256), 0, stream>>>(
        seed_xyz, inds_i, out + O_GRASP, out + O_GXYZ, out + O_FPG);

    // K5: stage C MLP (layers 1-2 to ws; layer 3 writes TRANSPOSED to out+O_VIEW)
    k5_gemm<<<dim3(4, 16, BB), dim3(256), 0, stream>>>(
        out + O_GFEAT, ws + W_W1T, b1, ws + W_SC1, m1, be1, ws + W_F1, 256, 256, 256, 1);
    k5_gemm<<<dim3(5, 16, BB), dim3(256), 0, stream>>>(
        ws + W_F1, ws + W_W2T, b2, ws + W_SC2, m2, be2, ws + W_F2, 300, 320, 256, 1);
    k5_gemm_t<<<dim3(5, 16, BB), dim3(256), 0, stream>>>(
        ws + W_F2, ws + W_W3T, b3, out + O_VIEW, 320, 300);

    // K6: view argmax + rotations (reads transposed view_score)
    k6_view<<<dim3(BB * SS / 256), dim3(256), 0, stream>>>(
        out + O_VIEW, ws + W_TMPL, out + O_TVI, out + O_TVS, out + O_VPX, out + O_VPR);
}

// Round 11
// 1173.250 us; speedup vs baseline: 1.2520x; 1.2520x over previous
//
#include <hip/hip_runtime.h>
#include <math.h>

// ---------------- problem constants ----------------
#define BB 4
#define NN 20000
#define CC 256
#define VV 300
#define SS 1024
#define CPKS 20480   // cpk per-batch stride (ceil(20000/512)*512)
#define W1RMAX 1536  // max M for single-wave reg-resident FPS (24 chunks * 64)
#define W4MAX 3072   // max M for 4-wave FPS (12 chunks * 256)

// output float offsets (concatenated flat, all read back as float32)
#define O_GRASP   0          // (4,20000)
#define O_OBJ     80000      // (4,20000)
#define O_GXYZ    160000     // (4,1024,3)
#define O_INDS    172288     // (4,1024)
#define O_GFEAT   176384     // (4,256,1024)
#define O_FPG     1224960    // (4,1024)
#define O_VIEW    1229056    // (4,1024,300)
#define O_TVI     2457856    // (4,1024)
#define O_TVS     2461952    // (4,1024)
#define O_VPX     2466048    // (4,1024,3)
#define O_VPR     2478336    // (4,1024,3,3)

// ws float offsets
#define W_GH1T    0          // [256 c][256 o]
#define W_W1T     65536      // [256 c][256 o]
#define W_W2T     131072     // [256 c][320 o-pad] (O=300)
#define W_W3T     212992     // [300 c][320 o-pad] (O=300)
#define W_TMPL    308992     // 300*3
#define W_SGH     309892     // 256
#define W_SC1     310148     // 256
#define W_SC2     310404     // 300
#define W_CNT     310704     // 4 ints (pad to 310720)
#define W_CPK     310720     // 4*20480 float4 (x,y,z,~idx-bits)
#define W_INDS    638400     // 4*1024 int
#define W_MASK    642496     // 4*20000 int
#define W_F1      722496     // 4*256*1024
#define W_F2      1771072    // 4*300*1024  (end 2999872 floats = 12 MB)

// FMA a 4-vector accumulator: A += W * X (componentwise), exact fmaf per element.
#define FMA4(A, W, X) do { \
    A.x = fmaf((W), (X).x, A.x); \
    A.y = fmaf((W), (X).y, A.y); \
    A.z = fmaf((W), (X).z, A.z); \
    A.w = fmaf((W), (X).w, A.w); } while (0)

__device__ __forceinline__ float4 bnrelu4(float4 a, float bb, float mm, float ssv, float ee) {
    float4 r;
    r.x = fmaxf(__fadd_rn(__fmul_rn(__fsub_rn(__fadd_rn(a.x, bb), mm), ssv), ee), 0.0f);
    r.y = fmaxf(__fadd_rn(__fmul_rn(__fsub_rn(__fadd_rn(a.y, bb), mm), ssv), ee), 0.0f);
    r.z = fmaxf(__fadd_rn(__fmul_rn(__fsub_rn(__fadd_rn(a.z, bb), mm), ssv), ee), 0.0f);
    r.w = fmaxf(__fadd_rn(__fmul_rn(__fsub_rn(__fadd_rn(a.w, bb), mm), ssv), ee), 0.0f);
    return r;
}

// ---- DPP-based wave64 max reduction on u64 keys (result broadcast to all lanes) ----
template <int CTRL>
__device__ __forceinline__ unsigned long long wmax_step(unsigned long long k) {
    int lo = (int)(unsigned int)k;
    int hi = (int)(unsigned int)(k >> 32);
    int plo = __builtin_amdgcn_update_dpp(lo, lo, CTRL, 0xf, 0xf, false);
    int phi = __builtin_amdgcn_update_dpp(hi, hi, CTRL, 0xf, 0xf, false);
    unsigned long long p = ((unsigned long long)(unsigned int)phi << 32) | (unsigned int)plo;
    return (p > k) ? p : k;
}
__device__ __forceinline__ unsigned long long wave_max_u64(unsigned long long k) {
    k = wmax_step<0x111>(k);   // row_shr:1
    k = wmax_step<0x112>(k);   // row_shr:2
    k = wmax_step<0x114>(k);   // row_shr:4
    k = wmax_step<0x118>(k);   // row_shr:8  -> lane15 of each row has row max
    k = wmax_step<0x142>(k);   // row_bcast15
    k = wmax_step<0x143>(k);   // row_bcast31 -> lane63 has wave max
    unsigned int lo = (unsigned int)__builtin_amdgcn_readlane((int)(unsigned int)k, 63);
    unsigned int hi = (unsigned int)__builtin_amdgcn_readlane((int)(unsigned int)(k >> 32), 63);
    return ((unsigned long long)hi << 32) | lo;
}

// ---- legacy register-resident storage (used by the >3072 fallback only) ----
// cpk.w stores ~n bits directly (sentinel stores 0).
template <int N> struct Pts {
    Pts<N - 1> rest;
    float px, py, pz, dist;
    unsigned int klo;
};
template <> struct Pts<0> {};

template <int N, int SH, int J0>
__device__ __forceinline__ void pts_load(Pts<N>& P, const float4* __restrict__ base,
                                         int t, int M,
                                         unsigned long long& bkey, float& bx, float& by, float& bz) {
    if constexpr (N > 0) {
        pts_load<N - 1, SH, J0>(P.rest, base, t, M, bkey, bx, by, bz);
        constexpr int J = J0 + N - 1;
        if ((J << SH) < M) {
            float4 v = base[t + (J << SH)];
            P.px = v.x; P.py = v.y; P.pz = v.z;
            P.klo = __float_as_uint(v.w);        // already ~n (pad -> 0)
            P.dist = (P.klo != 0u) ? 1e10f : 0.0f;
            unsigned long long k = ((unsigned long long)__float_as_uint(P.dist) << 32) | P.klo;
            if (k > bkey) { bkey = k; bx = v.x; by = v.y; bz = v.z; }
        } else {
            P.px = P.py = P.pz = 0.0f; P.dist = 0.0f; P.klo = 0u;
        }
    }
}

template <int N, int SH, int J0>
__device__ __forceinline__ void pts_upd(Pts<N>& P, int t, int M,
                                        float cx, float cy, float cz,
                                        unsigned long long& bkey, float& bx, float& by, float& bz) {
    if constexpr (N > 0) {
        pts_upd<N - 1, SH, J0>(P.rest, t, M, cx, cy, cz, bkey, bx, by, bz);
        constexpr int J = J0 + N - 1;
        if ((J << SH) < M) {
            float dx = __fsub_rn(P.px, cx);
            float dy = __fsub_rn(P.py, cy);
            float dz = __fsub_rn(P.pz, cz);
            float d = __fadd_rn(__fadd_rn(__fmul_rn(dx, dx), __fmul_rn(dy, dy)), __fmul_rn(dz, dz));
            float nd = fminf(P.dist, d);
            P.dist = nd;
            unsigned long long k = ((unsigned long long)__float_as_uint(nd) << 32) | P.klo;
            if (k > bkey) { bkey = k; bx = P.px; by = P.py; bz = P.pz; }
        }
    }
}

// ---------------- K0: prep (transposes, bn scales, templates, cnt=0) ----------------
__global__ void k0_prep(const float* __restrict__ w_gh1, const float* __restrict__ w1,
                        const float* __restrict__ w2, const float* __restrict__ w3,
                        const float* __restrict__ gh_g, const float* __restrict__ gh_v,
                        const float* __restrict__ g1, const float* __restrict__ v1,
                        const float* __restrict__ g2, const float* __restrict__ v2,
                        float* __restrict__ ws) {
    int id = blockIdx.x * 256 + threadIdx.x;
    if (id < 65536) {
        int k = id & 255, o = id >> 8;
        ws[W_GH1T + k * 256 + o] = w_gh1[id];
    } else if (id < 131072) {
        int l = id - 65536; int k = l & 255, o = l >> 8;
        ws[W_W1T + k * 256 + o] = w1[l];
    } else if (id < 207872) {
        int l = id - 131072; int k = l & 255, o = l >> 8;
        ws[W_W2T + k * 320 + o] = w2[l];
    } else if (id < 297872) {
        int l = id - 207872; int k = l % 300, o = l / 300;
        ws[W_W3T + k * 320 + o] = w3[l];
    } else if (id < 298172) {
        int i = id - 297872;
        double phi = (sqrt(5.0) - 1.0) / 2.0;
        double zi = (2.0 * (double)i + 1.0) / 300.0 - 1.0;
        double r2 = 1.0 - zi * zi; if (r2 < 0.0) r2 = 0.0;
        double ri = sqrt(r2);
        double th = (6.283185307179586 * (double)i) * phi;
        ws[W_TMPL + i * 3 + 0] = (float)(ri * cos(th));
        ws[W_TMPL + i * 3 + 1] = (float)(ri * sin(th));
        ws[W_TMPL + i * 3 + 2] = (float)zi;
    } else if (id < 298428) {
        int i = id - 298172; ws[W_SGH + i] = gh_g[i] / sqrtf(gh_v[i] + 1e-5f);
    } else if (id < 298684) {
        int i = id - 298428; ws[W_SC1 + i] = g1[i] / sqrtf(v1[i] + 1e-5f);
    } else if (id < 298984) {
        int i = id - 298684; ws[W_SC2 + i] = g2[i] / sqrtf(v2[i] + 1e-5f);
    } else if (id < 298988) {
        ((int*)(ws + W_CNT))[id - 298984] = 0;
    }
}

// ---------------- K1: fused stage A (64-wide n-tile, named float4 accumulators) ----------------
__global__ __launch_bounds__(256)
__attribute__((amdgpu_waves_per_eu(2, 2)))
void k1_stageA(
    const float* __restrict__ x,       // seed_features (B,256,20000)
    const float* __restrict__ wt,      // gh_w1^T [c][256]
    const float* __restrict__ b1g, const float* __restrict__ scg,
    const float* __restrict__ m1g, const float* __restrict__ be1g,
    const float* __restrict__ w2g, const float* __restrict__ b2g,   // (3,256),(3)
    float* __restrict__ out_grasp, float* __restrict__ out_obj, int* __restrict__ maskw) {
    __shared__ __align__(16) float Xs[256 * 64];   // 64 KB
    int b = blockIdx.y;
    int n0 = blockIdx.x * 64;
    int t = threadIdx.x;
    const float* xb = x + (size_t)b * CC * NN;
    #pragma unroll
    for (int k = 0; k < 16; k++) {
        int id = t + k * 256; int c = id >> 4; int u = id & 15;
        int n = n0 + u * 4;
        float4 v = make_float4(0.f, 0.f, 0.f, 0.f);
        if (n < NN) v = *(const float4*)(xb + (size_t)c * NN + n);
        *(float4*)(Xs + c * 64 + u * 4) = v;
    }
    __syncthreads();
    int og = (t >> 3) * 8;
    int n8 = (t & 7) * 8;
    float4 a0l = {0,0,0,0}, a0h = {0,0,0,0}, a1l = {0,0,0,0}, a1h = {0,0,0,0};
    float4 a2l = {0,0,0,0}, a2h = {0,0,0,0}, a3l = {0,0,0,0}, a3h = {0,0,0,0};
    float4 a4l = {0,0,0,0}, a4h = {0,0,0,0}, a5l = {0,0,0,0}, a5h = {0,0,0,0};
    float4 a6l = {0,0,0,0}, a6h = {0,0,0,0}, a7l = {0,0,0,0}, a7h = {0,0,0,0};
    #pragma unroll 2
    for (int c = 0; c < 256; c++) {
        float4 wva = *(const float4*)(wt + c * 256 + og);
        float4 wvb = *(const float4*)(wt + c * 256 + og + 4);
        float4 xva = *(const float4*)(Xs + c * 64 + n8);
        float4 xvb = *(const float4*)(Xs + c * 64 + n8 + 4);
        FMA4(a0l, wva.x, xva); FMA4(a0h, wva.x, xvb);
        FMA4(a1l, wva.y, xva); FMA4(a1h, wva.y, xvb);
        FMA4(a2l, wva.z, xva); FMA4(a2h, wva.z, xvb);
        FMA4(a3l, wva.w, xva); FMA4(a3h, wva.w, xvb);
        FMA4(a4l, wvb.x, xva); FMA4(a4h, wvb.x, xvb);
        FMA4(a5l, wvb.y, xva); FMA4(a5h, wvb.y, xvb);
        FMA4(a6l, wvb.z, xva); FMA4(a6h, wvb.z, xvb);
        FMA4(a7l, wvb.w, xva); FMA4(a7h, wvb.w, xvb);
    }
    __syncthreads();   // all reads of Xs done; reuse as h-tile
#define K1_EPI(I) { int o = og + I; \
    float bb = b1g[o], mm = m1g[o], ssv = scg[o], ee = be1g[o]; \
    *(float4*)(Xs + o * 64 + n8)     = bnrelu4(a##I##l, bb, mm, ssv, ee); \
    *(float4*)(Xs + o * 64 + n8 + 4) = bnrelu4(a##I##h, bb, mm, ssv, ee); }
    K1_EPI(0) K1_EPI(1) K1_EPI(2) K1_EPI(3)
    K1_EPI(4) K1_EPI(5) K1_EPI(6) K1_EPI(7)
#undef K1_EPI
    __syncthreads();
    if (t < 64) {
        float s0a = 0.0f, s1a = 0.0f, s2a = 0.0f;
        for (int c = 0; c < 256; c++) {
            float xv = Xs[c * 64 + t];
            s0a = fmaf(xv, w2g[c], s0a);
            s1a = fmaf(xv, w2g[256 + c], s1a);
            s2a = fmaf(xv, w2g[512 + c], s2a);
        }
        int n = n0 + t;
        if (n < NN) {
            float s0 = __fadd_rn(s0a, b2g[0]);
            float s1 = __fadd_rn(s1a, b2g[1]);
            float s2 = __fadd_rn(s2a, b2g[2]);
            bool obj = s1 > s0;
            bool gr = obj && (s2 > 0.1f);
            int gn = b * NN + n;
            out_grasp[gn] = s2;
            out_obj[gn] = obj ? 1.0f : 0.0f;
            maskw[gn] = gr ? 1 : 0;
        }
    }
}

// ---------------- K2: compact masked points (wave-aggregated atomics) ----------------
// w stores ~n bits (klo) directly.
__global__ void k2_compact(const float* __restrict__ sx, const int* __restrict__ maskr,
                           int* __restrict__ cnt, float4* __restrict__ cpk) {
    int n = blockIdx.x * 256 + threadIdx.x;
    int b = blockIdx.y;
    bool take = (n < NN) && (maskr[b * NN + n] != 0);
    unsigned long long m = __ballot(take);
    if (take) {
        int lane = threadIdx.x & 63;
        int lead = __ffsll((long long)m) - 1;
        int base = 0;
        if (lane == lead) base = atomicAdd(cnt + b, __popcll(m));
        base = __shfl(base, lead);
        int pos = base + __popcll(m & ((1ull << lane) - 1ull));
        const float* p = sx + ((size_t)b * NN + n) * 3;
        cpk[b * CPKS + pos] = make_float4(p[0], p[1], p[2], __uint_as_float(~(unsigned int)n));
    }
}

// ---------------- K2b: pad cpk to a 512-multiple with sentinel points ----------------
__global__ void k2_pad(const int* __restrict__ cnt, float4* __restrict__ cpk) {
    int b = blockIdx.x;
    int M = cnt[b];
    int Mpad = (M + 511) & ~511;
    for (int i = M + threadIdx.x; i < Mpad; i += 512)
        cpk[b * CPKS + i] = make_float4(0.f, 0.f, 0.f, __uint_as_float(0u));
}

// ---------------- K3w1r: FPS — SINGLE WAVE, fully register-resident ----------------
// r9 synthesis: at M<=1536, w4's step is ~85% exchange overhead (1640 cyc, update
// only ~204) while a single wave's tail is ~250 cyc (DPP+ballot+readlane; no
// barrier, no LDS combine, no publish). 24 chunks x 5 fields = 120 register
// fields = the PROVEN R0 SROA size (Pts<24> -> VGPR 132, zero scratch).
// Predicted ~1050-1100 cyc/step.
template <int NCH>
__global__ __launch_bounds__(64)
__attribute__((amdgpu_waves_per_eu(1, 1)))
void k3_fps_w1r(const float4* __restrict__ cpk,
                const int* __restrict__ cnt,
                float* __restrict__ out_inds,
                int* __restrict__ inds_i) {
    __shared__ unsigned int res[SS];
    int b = blockIdx.x;
    int t = threadIdx.x;   // 0..63
    int M = __builtin_amdgcn_readfirstlane(cnt[b]);
    if constexpr (NCH == 8) {
        if (M == 0) {
            for (int s = t; s < SS; s += 64) { out_inds[b * SS + s] = 0.0f; inds_i[b * SS + s] = 0; }
            return;
        }
    }
    if (8 * ((M + 511) >> 9) != NCH) return;   // exactly one variant proceeds

    float px[NCH], py[NCH], pz[NCH], dist[NCH];
    unsigned int klo[NCH];
    unsigned long long bkey = 0ull;
    float bx = 0.0f, by = 0.0f, bz = 0.0f;
    const float4* gsrc = cpk + b * CPKS;
    // branch-free init: [0, NCH*64) is real data or sentinels (NCH*64 == Mpad512)
    #pragma unroll
    for (int j = 0; j < NCH; j++) {
        float4 v = gsrc[t + (j << 6)];
        px[j] = v.x; py[j] = v.y; pz[j] = v.z;
        klo[j] = __float_as_uint(v.w);            // ~n; pad -> 0
        dist[j] = (klo[j] != 0u) ? 1e10f : 0.0f;  // sentinel -> key 0 forever
        unsigned long long k = ((unsigned long long)__float_as_uint(dist[j]) << 32) | klo[j];
        bool g = k > bkey;
        bkey = g ? k : bkey;
        bx = g ? v.x : bx; by = g ? v.y : by; bz = g ? v.z : bz;
    }
    for (int step = 0; step < SS; step++) {
        // wave argmax over u64 keys (winner unique: klo unique per real point)
        unsigned long long wkey = wave_max_u64(bkey);
        if (t == 0) res[step] = (unsigned int)(wkey & 0xFFFFFFFFull);   // klo; ~ at writeback
        if (step == SS - 1) break;   // last selection needs no update
        unsigned long long mb = __ballot(bkey == wkey);
        int wl = __ffsll((long long)mb) - 1;   // uniform winner lane
        float cx = __int_as_float(__builtin_amdgcn_readlane(__float_as_int(bx), wl));
        float cy = __int_as_float(__builtin_amdgcn_readlane(__float_as_int(by), wl));
        float cz = __int_as_float(__builtin_amdgcn_readlane(__float_as_int(bz), wl));
        bkey = 0ull; bx = by = bz = 0.0f;
        #pragma unroll
        for (int j = 0; j < NCH; j++) {
            float dx = __fsub_rn(px[j], cx);
            float dy = __fsub_rn(py[j], cy);
            float dz = __fsub_rn(pz[j], cz);
            float d = __fadd_rn(__fadd_rn(__fmul_rn(dx, dx), __fmul_rn(dy, dy)), __fmul_rn(dz, dz));
            float nd = fminf(dist[j], d);
            dist[j] = nd;
            unsigned long long k = ((unsigned long long)__float_as_uint(nd) << 32) | klo[j];
            bool g = k > bkey;
            bkey = g ? k : bkey;
            bx = g ? px[j] : bx; by = g ? py[j] : by; bz = g ? pz[j] : bz;
        }
    }
    __syncthreads();   // single wave: drains lgkmcnt before res readback
    for (int s = t; s < SS; s += 64) {
        unsigned int cid = ~res[s];
        out_inds[b * SS + s] = (float)cid;
        inds_i[b * SS + s] = (int)cid;
    }
}

// ---------------- K3w4: FPS — 4 waves (1/SIMD), reg-resident, slim exchange ----------------
// PROVEN at 700 us (r8). Handles 1536 < M <= 3072 (NCH = 2*ceil(M/512) in {8,10,12}).
template <int NCH>
__global__ __launch_bounds__(256)
__attribute__((amdgpu_waves_per_eu(1, 1)))
void k3_fps_w4(const float4* __restrict__ cpk,
               const int* __restrict__ cnt,
               float* __restrict__ out_inds,
               int* __restrict__ inds_i) {
    __shared__ unsigned long long skey[2][4];
    __shared__ __align__(16) float4 scd[2][4];
    __shared__ unsigned int res[SS];
    int b = blockIdx.x;
    int t = threadIdx.x;
    int wid = t >> 6, lane = t & 63;
    int M = __builtin_amdgcn_readfirstlane(cnt[b]);
    if (2 * ((M + 511) >> 9) != NCH) return;   // exactly one variant proceeds

    float px[NCH], py[NCH], pz[NCH], dist[NCH];
    unsigned int klo[NCH];
    unsigned long long bkey = 0ull;
    float bx = 0.0f, by = 0.0f, bz = 0.0f;
    const float4* gsrc = cpk + b * CPKS;
    #pragma unroll
    for (int j = 0; j < NCH; j++) {
        float4 v = gsrc[t + (j << 8)];
        px[j] = v.x; py[j] = v.y; pz[j] = v.z;
        klo[j] = __float_as_uint(v.w);            // ~n; pad -> 0
        dist[j] = (klo[j] != 0u) ? 1e10f : 0.0f;
        unsigned long long k = ((unsigned long long)__float_as_uint(dist[j]) << 32) | klo[j];
        bool g = k > bkey;
        bkey = g ? k : bkey;
        bx = g ? v.x : bx; by = g ? v.y : by; bz = g ? v.z : bz;
    }
    {
        unsigned long long wkey = wave_max_u64(bkey);
        unsigned long long mb = __ballot(bkey == wkey);
        if (lane == __ffsll((long long)mb) - 1) {
            skey[0][wid] = wkey;
            scd[0][wid] = make_float4(bx, by, bz, 0.0f);
        }
    }
    __syncthreads();
    int buf = 0;
    for (int step = 0; step < SS; step++) {
        unsigned long long wk = skey[buf][0];
        float4 c = scd[buf][0];
        #pragma unroll
        for (int i = 1; i < 4; i++) {
            unsigned long long k2 = skey[buf][i];
            float4 c2 = scd[buf][i];
            if (k2 > wk) { wk = k2; c = c2; }
        }
        if (t == 0) res[step] = (unsigned int)(wk & 0xFFFFFFFFull);
        if (step == SS - 1) break;
        float cx = c.x, cy = c.y, cz = c.z;
        bkey = 0ull; bx = by = bz = 0.0f;
        #pragma unroll
        for (int j = 0; j < NCH; j++) {
            float dx = __fsub_rn(px[j], cx);
            float dy = __fsub_rn(py[j], cy);
            float dz = __fsub_rn(pz[j], cz);
            float d = __fadd_rn(__fadd_rn(__fmul_rn(dx, dx), __fmul_rn(dy, dy)), __fmul_rn(dz, dz));
            float nd = fminf(dist[j], d);
            dist[j] = nd;
            unsigned long long k = ((unsigned long long)__float_as_uint(nd) << 32) | klo[j];
            bool g = k > bkey;
            bkey = g ? k : bkey;
            bx = g ? px[j] : bx; by = g ? py[j] : by; bz = g ? pz[j] : bz;
        }
        unsigned long long wkey = wave_max_u64(bkey);
        unsigned long long mb = __ballot(bkey == wkey);
        if (lane == __ffsll((long long)mb) - 1) {
            skey[buf ^ 1][wid] = wkey;
            scd[buf ^ 1][wid] = make_float4(bx, by, bz, 0.0f);
        }
        __syncthreads();   // no outstanding global ops in-loop -> cheap drain
        buf ^= 1;
    }
    __syncthreads();
    for (int s = t; s < SS; s += 256) {
        unsigned int cid = ~res[s];
        out_inds[b * SS + s] = (float)cid;
        inds_i[b * SS + s] = (int)cid;
    }
}

// ---------------- K3: FPS fallback — 512 thr / 8 waves (only if M > W4MAX) ----------------
template <int G>
__global__ __launch_bounds__(512)
__attribute__((amdgpu_waves_per_eu(2, 2)))
void k3_fps(const float4* __restrict__ cpk,
            const int* __restrict__ cnt,
            float* __restrict__ out_inds,
            int* __restrict__ inds_i, int minM) {
    int b = blockIdx.x;
    int t = threadIdx.x;
    int M = __builtin_amdgcn_readfirstlane(cnt[b]);
    if (M <= minM) return;
    __shared__ unsigned long long skey[2][8];
    __shared__ __align__(16) float4 scd[2][8];
    Pts<G> Pa, Pb;
    int wid = t >> 6, lane = t & 63;
    unsigned long long bkey = 0ull;
    float bx = 0, by = 0, bz = 0;
    const float4* base = cpk + b * CPKS;
    pts_load<G, 9, 0>(Pa, base, t, M, bkey, bx, by, bz);
    pts_load<G, 9, G>(Pb, base, t, M, bkey, bx, by, bz);
    {
        unsigned long long wkey = wave_max_u64(bkey);
        unsigned long long mb = __ballot(bkey == wkey);
        if (lane == __ffsll((long long)mb) - 1) {
            skey[0][wid] = wkey;
            scd[0][wid] = make_float4(bx, by, bz, 0.0f);
        }
    }
    __syncthreads();
    int buf = 0;
    for (int step = 0; step < SS; step++) {
        unsigned long long wk = skey[buf][0];
        float4 c = scd[buf][0];
        #pragma unroll
        for (int i = 1; i < 8; i++) {
            unsigned long long k2 = skey[buf][i];
            float4 c2 = scd[buf][i];
            if (k2 > wk) { wk = k2; c = c2; }
        }
        unsigned int cid = ~(unsigned int)(wk & 0xFFFFFFFFull);
        if (t == 0) { out_inds[b * SS + step] = (float)cid; inds_i[b * SS + step] = (int)cid; }
        bkey = 0ull; bx = by = bz = 0.0f;
        pts_upd<G, 9, 0>(Pa, t, M, c.x, c.y, c.z, bkey, bx, by, bz);
        pts_upd<G, 9, G>(Pb, t, M, c.x, c.y, c.z, bkey, bx, by, bz);
        unsigned long long wkey = wave_max_u64(bkey);
        unsigned long long mb = __ballot(bkey == wkey);
        if (lane == __ffsll((long long)mb) - 1) {
            skey[buf ^ 1][wid] = wkey;
            scd[buf ^ 1][wid] = make_float4(bx, by, bz, 0.0f);
        }
        __syncthreads();
        buf ^= 1;
    }
}

// ---------------- K4a: feature gather (one thread per output element) ----------------
__global__ void k4_gatherF(const float* __restrict__ sf, const int* __restrict__ inds,
                           float* __restrict__ o_feat) {
    int id = blockIdx.x * 256 + threadIdx.x;   // B*C*S = 1,048,576
    int s = id & (SS - 1);
    int bc = id >> 10;                          // b*C + c
    int b = bc >> 8;
    int idx = inds[(b << 10) | s];
    o_feat[id] = sf[(size_t)bc * NN + idx];
}

// ---------------- K4b: xyz + graspness gather ----------------
__global__ void k4_gatherX(const float* __restrict__ sx, const int* __restrict__ inds,
                           const float* __restrict__ grasp_all,
                           float* __restrict__ o_xyz, float* __restrict__ o_fg) {
    int id = blockIdx.x * 256 + threadIdx.x;   // 4096
    int b = id >> 10;
    int idx = inds[id];
    const float* p = sx + ((size_t)b * NN + idx) * 3;
    o_xyz[id * 3 + 0] = p[0];
    o_xyz[id * 3 + 1] = p[1];
    o_xyz[id * 3 + 2] = p[2];
    o_fg[id] = grasp_all[b * NN + idx];
}

// ---------------- K5: generic conv1x1 GEMM over 1024 pts (+optional bn+relu) ----------------
__global__ __launch_bounds__(256)
__attribute__((amdgpu_waves_per_eu(2, 2)))
void k5_gemm(const float* __restrict__ X, const float* __restrict__ WT,
             const float* __restrict__ bias, const float* __restrict__ scale,
             const float* __restrict__ mean, const float* __restrict__ beta,
             float* __restrict__ Y, int O, int Opad, int K, int relu_bn) {
    __shared__ __align__(16) float Xs[64 * 64];
    int b = blockIdx.z;
    int n0 = blockIdx.y * 64;
    int o0 = blockIdx.x * 64;
    int t = threadIdx.x;
    int o4 = o0 + (t & 15) * 4;
    int n4 = (t >> 4) * 4;
    float4 ac0 = {0,0,0,0}, ac1 = {0,0,0,0}, ac2 = {0,0,0,0}, ac3 = {0,0,0,0};
    const float* Xb = X + (size_t)b * K * SS;
    for (int c0 = 0; c0 < K; c0 += 64) {
        #pragma unroll
        for (int k = 0; k < 4; k++) {
            int id = t + k * 256; int cc = id >> 4; int nn4 = (id & 15) * 4;
            int c = c0 + cc;
            float4 v = make_float4(0.f, 0.f, 0.f, 0.f);
            if (c < K) v = *(const float4*)(Xb + (size_t)c * SS + n0 + nn4);
            *(float4*)(Xs + cc * 64 + nn4) = v;
        }
        __syncthreads();
        int kmax = (K - c0 < 64) ? (K - c0) : 64;
        for (int cc = 0; cc < kmax; cc++) {
            float4 wv = *(const float4*)(WT + (size_t)(c0 + cc) * Opad + o4);
            float4 xv = *(const float4*)(Xs + cc * 64 + n4);
            FMA4(ac0, wv.x, xv);
            FMA4(ac1, wv.y, xv);
            FMA4(ac2, wv.z, xv);
            FMA4(ac3, wv.w, xv);
        }
        __syncthreads();
    }
#define K5_EPI(I) { int o = o4 + I; if (o < O) { \
    float bb = bias[o]; float4 v; \
    if (relu_bn) { v = bnrelu4(ac##I, bb, mean[o], scale[o], beta[o]); } \
    else { v.x = __fadd_rn(ac##I.x, bb); v.y = __fadd_rn(ac##I.y, bb); \
           v.z = __fadd_rn(ac##I.z, bb); v.w = __fadd_rn(ac##I.w, bb); } \
    *(float4*)(Y + ((size_t)b * O + o) * SS + n0 + n4) = v; } }
    K5_EPI(0) K5_EPI(1) K5_EPI(2) K5_EPI(3)
#undef K5_EPI
}

// ---------------- K5t: layer-3 GEMM with TRANSPOSED epilogue (replaces K7) ----------------
__global__ __launch_bounds__(256)
__attribute__((amdgpu_waves_per_eu(2, 2)))
void k5_gemm_t(const float* __restrict__ X, const float* __restrict__ WT,
               const float* __restrict__ bias,
               float* __restrict__ Y, int Opad, int K) {
    __shared__ __align__(16) float Xs[64 * 64];
    int b = blockIdx.z;
    int n0 = blockIdx.y * 64;
    int o0 = blockIdx.x * 64;
    int t = threadIdx.x;
    int o4 = o0 + (t & 15) * 4;
    int n4 = (t >> 4) * 4;
    float4 ac0 = {0,0,0,0}, ac1 = {0,0,0,0}, ac2 = {0,0,0,0}, ac3 = {0,0,0,0};
    const float* Xb = X + (size_t)b * K * SS;
    for (int c0 = 0; c0 < K; c0 += 64) {
        #pragma unroll
        for (int k = 0; k < 4; k++) {
            int id = t + k * 256; int cc = id >> 4; int nn4 = (id & 15) * 4;
            int c = c0 + cc;
            float4 v = make_float4(0.f, 0.f, 0.f, 0.f);
            if (c < K) v = *(const float4*)(Xb + (size_t)c * SS + n0 + nn4);
            *(float4*)(Xs + cc * 64 + nn4) = v;
        }
        __syncthreads();
        int kmax = (K - c0 < 64) ? (K - c0) : 64;
        for (int cc = 0; cc < kmax; cc++) {
            float4 wv = *(const float4*)(WT + (size_t)(c0 + cc) * Opad + o4);
            float4 xv = *(const float4*)(Xs + cc * 64 + n4);
            FMA4(ac0, wv.x, xv);
            FMA4(ac1, wv.y, xv);
            FMA4(ac2, wv.z, xv);
            FMA4(ac3, wv.w, xv);
        }
        __syncthreads();
    }
    if (o4 + 3 < VV) {   // o4 multiple of 4; VV=300 -> o4 <= 296 fully in-bounds
        float4 bb4 = *(const float4*)(bias + o4);
#define K5T_ROW(J, CMP) { \
        float4 r; \
        r.x = __fadd_rn(ac0.CMP, bb4.x); \
        r.y = __fadd_rn(ac1.CMP, bb4.y); \
        r.z = __fadd_rn(ac2.CMP, bb4.z); \
        r.w = __fadd_rn(ac3.CMP, bb4.w); \
        *(float4*)(Y + ((size_t)b * SS + (n0 + n4 + J)) * VV + o4) = r; }
        K5T_ROW(0, x) K5T_ROW(1, y) K5T_ROW(2, z) K5T_ROW(3, w)
#undef K5T_ROW
    }
}

// ---------------- K6: view max/argmax + rotations (float4-vectorized scan) ----------------
__global__ void k6_view(const float* __restrict__ Vs,   // view_score (B,1024,300)
                        const float* __restrict__ tmpl,
                        float* __restrict__ o_ti, float* __restrict__ o_ts,
                        float* __restrict__ o_vx, float* __restrict__ o_vr) {
    int id = blockIdx.x * 256 + threadIdx.x;   // 4096
    const float4* f4 = (const float4*)(Vs + (size_t)id * VV);
    float best = -INFINITY;
    int bi = 0;
    #pragma unroll 5
    for (int g = 0; g < VV / 4; g++) {
        float4 x4 = f4[g];
        if (x4.x > best) { best = x4.x; bi = g * 4; }       // in-order strict > keeps
        if (x4.y > best) { best = x4.y; bi = g * 4 + 1; }   // first max (== reference)
        if (x4.z > best) { best = x4.z; bi = g * 4 + 2; }
        if (x4.w > best) { best = x4.w; bi = g * 4 + 3; }
    }
    o_ti[id] = (float)bi;
    o_ts[id] = best;
    float tx = tmpl[bi * 3 + 0], ty = tmpl[bi * 3 + 1], tz = tmpl[bi * 3 + 2];
    o_vx[id * 3 + 0] = tx; o_vx[id * 3 + 1] = ty; o_vx[id * 3 + 2] = tz;
    // towards = -vp_xyz
    float ax0 = -tx, ax1 = -ty, ax2 = -tz;
    float ay0 = ty, ay1 = -tx, ay2 = 0.0f;   // (-ax1, ax0, 0)
    float ny = sqrtf(__fadd_rn(__fadd_rn(__fmul_rn(ay0, ay0), __fmul_rn(ay1, ay1)), __fmul_rn(ay2, ay2)));
    if (ny == 0.0f) { ay0 = 0.0f; ay1 = 1.0f; ay2 = 0.0f; }
    float nx = sqrtf(__fadd_rn(__fadd_rn(__fmul_rn(ax0, ax0), __fmul_rn(ax1, ax1)), __fmul_rn(ax2, ax2)));
    ax0 = ax0 / nx; ax1 = ax1 / nx; ax2 = ax2 / nx;
    float ny2 = sqrtf(__fadd_rn(__fadd_rn(__fmul_rn(ay0, ay0), __fmul_rn(ay1, ay1)), __fmul_rn(ay2, ay2)));
    ay0 = ay0 / ny2; ay1 = ay1 / ny2; ay2 = ay2 / ny2;
    float az0 = __fsub_rn(__fmul_rn(ax1, ay2), __fmul_rn(ax2, ay1));
    float az1 = __fsub_rn(__fmul_rn(ax2, ay0), __fmul_rn(ax0, ay2));
    float az2 = __fsub_rn(__fmul_rn(ax0, ay1), __fmul_rn(ax1, ay0));
    float* R = o_vr + (size_t)id * 9;   // columns = (ax, ay, az)
    R[0] = ax0; R[1] = ay0; R[2] = az0;
    R[3] = ax1; R[4] = ay1; R[5] = az1;
    R[6] = ax2; R[7] = ay2; R[8] = az2;
}

extern "C" void kernel_launch(void* const* d_in, const int* in_sizes, int n_in,
                              void* d_out, int out_size, void* d_ws, size_t ws_size,
                              hipStream_t stream) {
    const float* seed_xyz  = (const float*)d_in[0];
    const float* seed_feat = (const float*)d_in[1];
    const float* gh_w1 = (const float*)d_in[2];
    const float* gh_b1 = (const float*)d_in[3];
    const float* gh_g1 = (const float*)d_in[4];
    const float* gh_be1 = (const float*)d_in[5];
    const float* gh_m1 = (const float*)d_in[6];
    const float* gh_v1 = (const float*)d_in[7];
    const float* gh_w2 = (const float*)d_in[8];
    const float* gh_b2 = (const float*)d_in[9];
    const float* w1 = (const float*)d_in[10];
    const float* b1 = (const float*)d_in[11];
    const float* g1 = (const float*)d_in[12];
    const float* be1 = (const float*)d_in[13];
    const float* m1 = (const float*)d_in[14];
    const float* v1 = (const float*)d_in[15];
    const float* w2 = (const float*)d_in[16];
    const float* b2 = (const float*)d_in[17];
    const float* g2 = (const float*)d_in[18];
    const float* be2 = (const float*)d_in[19];
    const float* m2 = (const float*)d_in[20];
    const float* v2 = (const float*)d_in[21];
    const float* w3 = (const float*)d_in[22];
    const float* b3 = (const float*)d_in[23];

    float* out = (float*)d_out;
    float* ws = (float*)d_ws;
    int* cnt = (int*)(ws + W_CNT);
    float4* cpk = (float4*)(ws + W_CPK);
    int* inds_i = (int*)(ws + W_INDS);
    int* maskw = (int*)(ws + W_MASK);

    // K0: prep
    k0_prep<<<dim3((298988 + 255) / 256), dim3(256), 0, stream>>>(
        gh_w1, w1, w2, w3, gh_g1, gh_v1, g1, v1, g2, v2, ws);

    // K1: fused stage A (64-wide tiles)
    k1_stageA<<<dim3((NN + 63) / 64, BB), dim3(256), 0, stream>>>(
        seed_feat, ws + W_GH1T, gh_b1, ws + W_SGH, gh_m1, gh_be1, gh_w2, gh_b2,
        out + O_GRASP, out + O_OBJ, maskw);

    // K2: compaction (wave-aggregated atomics) + sentinel padding to 512-multiple
    k2_compact<<<dim3((NN + 255) / 256, BB), dim3(256), 0, stream>>>(seed_xyz, maskw, cnt, cpk);
    k2_pad<<<dim3(BB), dim3(512), 0, stream>>>(cnt, cpk);

    // K3: FPS — single-wave reg-resident (M <= 1536), 4-wave (<= 3072), fallback
    k3_fps_w1r<8><<<dim3(BB), dim3(64), 0, stream>>>(cpk, cnt, out + O_INDS, inds_i);
    k3_fps_w1r<16><<<dim3(BB), dim3(64), 0, stream>>>(cpk, cnt, out + O_INDS, inds_i);
    k3_fps_w1r<24><<<dim3(BB), dim3(64), 0, stream>>>(cpk, cnt, out + O_INDS, inds_i);
    k3_fps_w4<8><<<dim3(BB), dim3(256), 0, stream>>>(cpk, cnt, out + O_INDS, inds_i);
    k3_fps_w4<10><<<dim3(BB), dim3(256), 0, stream>>>(cpk, cnt, out + O_INDS, inds_i);
    k3_fps_w4<12><<<dim3(BB), dim3(256), 0, stream>>>(cpk, cnt, out + O_INDS, inds_i);
    k3_fps<20><<<dim3(BB), dim3(512), 0, stream>>>(cpk, cnt, out + O_INDS, inds_i, W4MAX);

    // K4: gathers
    k4_gatherF<<<dim3(BB * CC * SS / 256), dim3(256), 0, stream>>>(seed_feat, inds_i, out + O_GFEAT);
    k4_gatherX<<<dim3(BB * SS / 256), dim3(256), 0, stream>>>(
        seed_xyz, inds_i, out + O_GRASP, out + O_GXYZ, out + O_FPG);

    // K5: stage C MLP (layers 1-2 to ws; layer 3 writes TRANSPOSED to out+O_VIEW)
    k5_gemm<<<dim3(4, 16, BB), dim3(256), 0, stream>>>(
        out + O_GFEAT, ws + W_W1T, b1, ws + W_SC1, m1, be1, ws + W_F1, 256, 256, 256, 1);
    k5_gemm<<<dim3(5, 16, BB), dim3(256), 0, stream>>>(
        ws + W_F1, ws + W_W2T, b2, ws + W_SC2, m2, be2, ws + W_F2, 300, 320, 256, 1);
    k5_gemm_t<<<dim3(5, 16, BB), dim3(256), 0, stream>>>(
        ws + W_F2, ws + W_W3T, b3, out + O_VIEW, 320, 300);

    // K6: view argmax + rotations (reads transposed view_score)
    k6_view<<<dim3(BB * SS / 256), dim3(256), 0, stream>>>(
        out + O_VIEW, ws + W_TMPL, out + O_TVI, out + O_TVS, out + O_VPX, out + O_VPR);
}